// Round 12
// baseline (144.584 us; speedup 1.0000x reference)
//
#include <hip/hip_runtime.h>
#include <math.h>

typedef __bf16 bf16x8 __attribute__((ext_vector_type(8)));
typedef float  f32x4  __attribute__((ext_vector_type(4)));

#define B_    4
#define CIN   256
#define COUT  256
#define KK_   9
#define SD    512
#define H_    64
#define W_    64
#define HW    4096
#define KTOT  2304   // KK_*CIN ; k = kk*CIN + c
#define SCALE_     0.0208333333333333332f   // 1/sqrt(256*9)
#define MOD_SCALE_ 0.04419417382415922f     // 1/sqrt(512)
#define SQRT2_     1.4142135623730951f

__device__ __forceinline__ unsigned short f2bf(float f) {
    union { float f; unsigned int u; } v; v.f = f;
    unsigned int r = v.u + 0x7FFFu + ((v.u >> 16) & 1u);   // RNE
    return (unsigned short)(r >> 16);
}

__device__ __forceinline__ void gload_lds16(const void* g, void* l) {
    __builtin_amdgcn_global_load_lds(
        (const __attribute__((address_space(1))) unsigned int*)g,
        (__attribute__((address_space(3))) unsigned int*)l, 16, 0, 0);
}

// ---------------- kernel 1: style modulation ----------------
__global__ void k_style(const float* __restrict__ style, const float* __restrict__ mod_w,
                        const float* __restrict__ mod_b, float* __restrict__ s_buf) {
    int b = blockIdx.x, c = threadIdx.x;
    const float* st = style + b * SD;
    const float* mw = mod_w + c * SD;
    float acc = 0.f;
    for (int d = 0; d < SD; ++d) acc += st[d] * mw[d];
    s_buf[b * CIN + c] = acc * MOD_SCALE_ + mod_b[c];
}

// ---------------- kernel 2: demodulated weights, bf16, o-major, coalesced stores ----
// wgtT2[b][o][k], k = kk*CIN + c
__global__ void k_wgt(const float* __restrict__ weight, const float* __restrict__ s_buf,
                      unsigned short* __restrict__ wgtT2) {
    int o = blockIdx.x, b = blockIdx.y;
    int c = threadIdx.x;
    float s = s_buf[b * CIN + c];
    const float* wp = weight + (o * CIN + c) * KK_;
    float w[KK_];
    float p = 0.f;
#pragma unroll
    for (int i = 0; i < KK_; ++i) { w[i] = SCALE_ * wp[i] * s; p += w[i] * w[i]; }
    __shared__ float red[256];
    red[c] = p;
    __syncthreads();
    for (int s2 = 128; s2 > 0; s2 >>= 1) {
        if (c < s2) red[c] += red[c + s2];
        __syncthreads();
    }
    float demod = rsqrtf(red[0] + 1e-8f);
    __shared__ unsigned short wbuf[KK_][256];
#pragma unroll
    for (int i = 0; i < KK_; ++i) wbuf[i][c] = f2bf(w[i] * demod);
    __syncthreads();
    unsigned int* dst = (unsigned int*)(wgtT2 + ((size_t)(b * COUT + o)) * KTOT);
#pragma unroll
    for (int e = 0; e < KK_ / 2 + 1; ++e) {
        int idx = c + e * 256;
        if (idx < (KK_ * 256) / 2) {
            int k0 = idx * 2;
            int kk = k0 >> 8, cc = k0 & 255;
            dst[idx] = (unsigned int)wbuf[kk][cc] | ((unsigned int)wbuf[kk][cc + 1] << 16);
        }
    }
}

// ---------------- kernel 2b: input transpose -> in_t[b][y][x][c] bf16 ----------------
__global__ __launch_bounds__(256) void k_tr(const float* __restrict__ in,
                                            unsigned short* __restrict__ in_t) {
    const int y = blockIdx.x, cc = blockIdx.y, b = blockIdx.z;
    const int tid = threadIdx.x;
    __shared__ unsigned short t[64][65];
    for (int e = tid; e < 4096; e += 256) {
        int c = e >> 6, x = e & 63;
        t[c][x] = f2bf(in[((size_t)(b * CIN + cc * 64 + c)) * HW + y * W_ + x]);
    }
    __syncthreads();
    for (int e = tid; e < 2048; e += 256) {
        int x = e >> 5, cp = e & 31;
        int c = cp * 2;
        unsigned int lo = t[c][x], hi = t[c + 1][x];
        unsigned int v = lo | (hi << 16);
        unsigned int* dst = (unsigned int*)(in_t + ((size_t)(b * HW + y * W_ + x)) * CIN + cc * 64);
        dst[cp] = v;
    }
}

// ---------------- kernel 3: deformable im2col -> smpT[b][p][k] bf16 ----------------
// grid (64 y, 9 kk, 4 b), block 256 = 4 waves.
__global__ __launch_bounds__(256) void k_im2col(
    const unsigned short* __restrict__ in_t, const float* __restrict__ off,
    const float* __restrict__ msk, unsigned short* __restrict__ smpT) {
    const int y  = blockIdx.x;
    const int kk = blockIdx.y;
    const int b  = blockIdx.z;
    const int tid = threadIdx.x;

    __shared__ float stw[4][64];
    __shared__ int   stix[4][64];   // pre-scaled by CIN

    if (tid < 64) {
        int x = tid;
        float oy = off[(((size_t)b * 2 * KK_ + 2 * kk + 0) * H_ + y) * W_ + x];
        float ox = off[(((size_t)b * 2 * KK_ + 2 * kk + 1) * H_ + y) * W_ + x];
        float m  = msk[(((size_t)b * KK_ + kk) * H_ + y) * W_ + x];
        float py = (float)(y + kk / 3 - 1) + oy;
        float px = (float)(x + kk % 3 - 1) + ox;
        float y0f = floorf(py), x0f = floorf(px);
        float dy = py - y0f, dx = px - x0f;
        int y0 = (int)y0f, x0 = (int)x0f;
        int y1 = y0 + 1, x1 = x0 + 1;
        bool vy0 = (y0 >= 0) & (y0 < H_), vy1 = (y1 >= 0) & (y1 < H_);
        bool vx0 = (x0 >= 0) & (x0 < W_), vx1 = (x1 >= 0) & (x1 < W_);
        int cy0 = min(max(y0, 0), H_ - 1), cy1 = min(max(y1, 0), H_ - 1);
        int cx0 = min(max(x0, 0), W_ - 1), cx1 = min(max(x1, 0), W_ - 1);
        float wy0 = 1.f - dy, wy1 = dy, wx0 = 1.f - dx, wx1 = dx;
        stw[0][x] = (vy0 && vx0) ? m * wy0 * wx0 : 0.f;  stix[0][x] = (cy0 * W_ + cx0) * CIN;
        stw[1][x] = (vy0 && vx1) ? m * wy0 * wx1 : 0.f;  stix[1][x] = (cy0 * W_ + cx1) * CIN;
        stw[2][x] = (vy1 && vx0) ? m * wy1 * wx0 : 0.f;  stix[2][x] = (cy1 * W_ + cx0) * CIN;
        stw[3][x] = (vy1 && vx1) ? m * wy1 * wx1 : 0.f;  stix[3][x] = (cy1 * W_ + cx1) * CIN;
    }
    __syncthreads();

    const unsigned short* base = in_t + (size_t)b * HW * CIN;
    const int l = tid & 63, w = tid >> 6;
    const int c0 = (l & 31) * 8;
    const int psub = l >> 5;
    unsigned short* drow = smpT + ((size_t)(b * HW + y * W_)) * KTOT + kk * CIN + c0;

#pragma unroll
    for (int i = 0; i < 4; ++i) {
        int pA = (w + i * 8) * 2 + psub;          // 0..63
        int pB = (w + i * 8 + 4) * 2 + psub;
        bf16x8 a0 = *(const bf16x8*)(base + stix[0][pA] + c0);
        bf16x8 a1 = *(const bf16x8*)(base + stix[1][pA] + c0);
        bf16x8 a2 = *(const bf16x8*)(base + stix[2][pA] + c0);
        bf16x8 a3 = *(const bf16x8*)(base + stix[3][pA] + c0);
        bf16x8 b0 = *(const bf16x8*)(base + stix[0][pB] + c0);
        bf16x8 b1 = *(const bf16x8*)(base + stix[1][pB] + c0);
        bf16x8 b2 = *(const bf16x8*)(base + stix[2][pB] + c0);
        bf16x8 b3 = *(const bf16x8*)(base + stix[3][pB] + c0);
        float wa0 = stw[0][pA], wa1 = stw[1][pA], wa2 = stw[2][pA], wa3 = stw[3][pA];
        float wb0 = stw[0][pB], wb1 = stw[1][pB], wb2 = stw[2][pB], wb3 = stw[3][pB];
        bf16x8 rA, rB;
#pragma unroll
        for (int j = 0; j < 8; ++j) {
            rA[j] = (__bf16)(wa0 * (float)a0[j] + wa1 * (float)a1[j]
                           + wa2 * (float)a2[j] + wa3 * (float)a3[j]);
            rB[j] = (__bf16)(wb0 * (float)b0[j] + wb1 * (float)b1[j]
                           + wb2 * (float)b2[j] + wb3 * (float)b3[j]);
        }
        *(bf16x8*)(drow + (size_t)pA * KTOT) = rA;
        *(bf16x8*)(drow + (size_t)pB * KTOT) = rB;
    }
}

// ---------------- kernel 4: bf16 MFMA GEMM, A direct-from-L2, B 4-deep LDS ----------
// C[o][p] = sum_k W[o][k] * S[p][k]. Tile 128(O) x 64(P), BK=64, 4 waves (wave 64x32).
// A (weights, L2-resident) loaded global->reg, double-buffered; B via global_load_lds
// (8-slot XOR swizzle), 4-deep, counted vmcnt. LDS = 32 KB only.
__global__ __launch_bounds__(256) void k_gemm(
    const unsigned short* __restrict__ wgtT2, const unsigned short* __restrict__ smpT,
    const float* __restrict__ bias1, const float* __restrict__ bias2,
    float* __restrict__ mid) {
    const int p0 = blockIdx.x * 64;
    const int o0 = blockIdx.y * 128;
    const int b  = blockIdx.z;
    const int tid = threadIdx.x;
    const int w  = tid >> 6, l = tid & 63;
    const int lo = l & 15, lg = l >> 4;
    const int wo = w >> 1, wp = w & 1;     // wave tile: 64 o x 32 p

    __shared__ unsigned short b_lds[4][64 * 64];    // 32 KB [p][k], 4-deep

    const unsigned short* Abase = wgtT2 + ((size_t)(b * COUT + o0)) * KTOT;
    const unsigned short* Bbase = smpT  + ((size_t)(b * HW   + p0)) * KTOT;

    f32x4 acc[4][2] = {};
    bf16x8 afA[4][2], afB[4][2];

    // B staging: 8KB = 512 16B-slots, 2 per thread
#define STAGE_B(T)                                                                       \
    do {                                                                                 \
        int kbase = (T) * 64;                                                            \
        unsigned short* dst = &b_lds[(T) & 3][0];                                        \
        _Pragma("unroll")                                                                \
        for (int i = 0; i < 2; ++i) {                                                    \
            int slin = i * 256 + tid;                                                    \
            int r = slin >> 3, s = slin & 7;                                             \
            gload_lds16(Bbase + (size_t)r * KTOT + kbase + ((s ^ (r & 7)) * 8),          \
                        dst + (size_t)slin * 8);                                         \
        }                                                                                \
    } while (0)

    // A fragments: direct global (L2-hit), no swizzle
#define LOADA(T, DST)                                                                    \
    do {                                                                                 \
        int kbase = (T) * 64;                                                            \
        _Pragma("unroll")                                                                \
        for (int mi = 0; mi < 4; ++mi) {                                                 \
            int R = wo * 64 + mi * 16 + lo;                                              \
            _Pragma("unroll")                                                            \
            for (int kki = 0; kki < 2; ++kki)                                            \
                DST[mi][kki] = *(const bf16x8*)(Abase + (size_t)R * KTOT + kbase         \
                                                + (kki * 4 + lg) * 8);                   \
        }                                                                                \
    } while (0)

#define COMPUTE(T, AF)                                                                   \
    do {                                                                                 \
        const unsigned short* bl = &b_lds[(T) & 3][0];                                   \
        bf16x8 bfr[2][2];                                                                \
        _Pragma("unroll")                                                                \
        for (int ni = 0; ni < 2; ++ni) {                                                 \
            int P = wp * 32 + ni * 16 + lo;                                              \
            _Pragma("unroll")                                                            \
            for (int kki = 0; kki < 2; ++kki)                                            \
                bfr[ni][kki] = *(const bf16x8*)&bl[P * 64 + (((kki * 4 + lg) ^ (P & 7)) * 8)]; \
        }                                                                                \
        _Pragma("unroll")                                                                \
        for (int kki = 0; kki < 2; ++kki)                                                \
            _Pragma("unroll")                                                            \
            for (int mi = 0; mi < 4; ++mi)                                               \
                _Pragma("unroll")                                                        \
                for (int ni = 0; ni < 2; ++ni)                                           \
                    acc[mi][ni] = __builtin_amdgcn_mfma_f32_16x16x32_bf16(               \
                        AF[mi][kki], bfr[ni][kki], acc[mi][ni], 0, 0, 0);                \
    } while (0)

    // prologue
    STAGE_B(0);
    STAGE_B(1);
    LOADA(0, afA);

    for (int t = 0; t < 34; t += 2) {
        // phase A: compute t (afA), prefetch A(t+1)->afB, stage B(t+2)
        __builtin_amdgcn_s_barrier();
        STAGE_B(t + 2);
        LOADA(t + 1, afB);
        asm volatile("s_waitcnt vmcnt(20)" ::: "memory");   // drains B(t); keeps B(t+1,2)+A in flight
        __builtin_amdgcn_sched_barrier(0);
        __builtin_amdgcn_s_barrier();
        COMPUTE(t, afA);
        // phase B: compute t+1 (afB), prefetch A(t+2)->afA, stage B(t+3)
        __builtin_amdgcn_s_barrier();
        STAGE_B(t + 3);
        LOADA(t + 2, afA);
        asm volatile("s_waitcnt vmcnt(20)" ::: "memory");
        __builtin_amdgcn_sched_barrier(0);
        __builtin_amdgcn_s_barrier();
        COMPUTE(t + 1, afB);
    }
    // tail: t = 34 (afA holds A(34)), 35
    __builtin_amdgcn_s_barrier();
    LOADA(35, afB);
    asm volatile("s_waitcnt vmcnt(10)" ::: "memory");       // drains B(34) (and B(35))
    __builtin_amdgcn_sched_barrier(0);
    __builtin_amdgcn_s_barrier();
    COMPUTE(34, afA);
    __builtin_amdgcn_s_barrier();
    asm volatile("s_waitcnt vmcnt(8)" ::: "memory");        // B(35) drained; A(35) handled by compiler
    __builtin_amdgcn_sched_barrier(0);
    __builtin_amdgcn_s_barrier();
    COMPUTE(35, afB);
#undef STAGE_B
#undef LOADA
#undef COMPUTE

    // epilogue: frag D mapping col=lo (p), row=lg*4+r (o)
    float* mb = mid + ((size_t)b * COUT) * HW;
#pragma unroll
    for (int mi = 0; mi < 4; ++mi) {
        int obase = o0 + wo * 64 + mi * 16 + lg * 4;
#pragma unroll
        for (int ni = 0; ni < 2; ++ni) {
            int p = p0 + wp * 32 + ni * 16 + lo;
#pragma unroll
            for (int r = 0; r < 4; ++r) {
                int oo = obase + r;
                float v = acc[mi][ni][r] + bias1[oo];
                v = (v > 0.f ? v : 0.2f * v) * SQRT2_;
                v += bias2[oo];
                v = (v > 0.f ? v : 0.2f * v) * SQRT2_;
                mb[(size_t)oo * HW + p] = v;
            }
        }
    }
}

// ---------------- kernel 5: separable x2-upsample FIR blur ----------------
__global__ __launch_bounds__(256) void k_blur(const float* __restrict__ mid,
                                              float* __restrict__ out) {
    const int bo = blockIdx.x;
    const int tid = threadIdx.x;
    __shared__ float m[64][64];
    __shared__ float vt[128][65];

    const float4* src = (const float4*)(mid + (size_t)bo * HW);
#pragma unroll
    for (int i = 0; i < 4; ++i)
        ((float4*)m)[tid + 256 * i] = src[tid + 256 * i];
    __syncthreads();

#pragma unroll
    for (int i = 0; i < 32; ++i) {
        int e = tid + 256 * i;
        int Y = e >> 6, x = e & 63;
        int h = Y >> 1;
        float acc;
        if (Y & 1) acc = 3.f * m[h][x] + ((h + 1 < 64) ? m[h + 1][x] : 0.f);
        else       acc = ((h >= 1) ? m[h - 1][x] : 0.f) + 3.f * m[h][x];
        vt[Y][x] = acc;
    }
    __syncthreads();

    float4* dst = (float4*)(out + (size_t)bo * 128 * 128);
#pragma unroll
    for (int i = 0; i < 16; ++i) {
        int e = tid + 256 * i;
        int Y = e >> 5, t = e & 31;
        const float* v = vt[Y];
        int c = 2 * t;
        float vm1 = (c >= 1) ? v[c - 1] : 0.f;
        float v0 = v[c];
        float v1 = v[c + 1];
        float vp2 = (c + 2 < 64) ? v[c + 2] : 0.f;
        float4 r;
        r.x = (vm1 + 3.f * v0) * (1.f / 16.f);
        r.y = (3.f * v0 + v1)  * (1.f / 16.f);
        r.z = (v0 + 3.f * v1)  * (1.f / 16.f);
        r.w = (3.f * v1 + vp2) * (1.f / 16.f);
        dst[e] = r;
    }
}

// ---------------- launch ----------------
extern "C" void kernel_launch(void* const* d_in, const int* in_sizes, int n_in,
                              void* d_out, int out_size, void* d_ws, size_t ws_size,
                              hipStream_t stream) {
    const float* input  = (const float*)d_in[0];
    const float* style  = (const float*)d_in[1];
    const float* offset = (const float*)d_in[2];
    const float* mask   = (const float*)d_in[3];
    const float* weight = (const float*)d_in[4];
    const float* mod_w  = (const float*)d_in[5];
    const float* mod_b  = (const float*)d_in[6];
    const float* bias1  = (const float*)d_in[7];
    const float* bias2  = (const float*)d_in[8];
    float* out = (float*)d_out;

    // ws layout (bytes): s_buf 4K | wgtT2 bf16 4.72M | smpT bf16 75.5M | X 16.8M
    // X region: in_t bf16 (8.4M, dead after k_im2col) aliased with mid f32 (16.8M).
    char* ws = (char*)d_ws;
    float*          s_buf = (float*)ws;
    unsigned short* wgtT2 = (unsigned short*)(ws + 4096);
    unsigned short* smpT  = (unsigned short*)(ws + 4096 + (size_t)B_ * COUT * KTOT * 2);
    char*           X     = ws + 4096 + (size_t)B_ * COUT * KTOT * 2 + (size_t)B_ * HW * KTOT * 2;
    unsigned short* in_t  = (unsigned short*)X;
    float*          mid   = (float*)X;

    k_style <<<dim3(B_), dim3(256), 0, stream>>>(style, mod_w, mod_b, s_buf);
    k_wgt   <<<dim3(COUT, B_), dim3(256), 0, stream>>>(weight, s_buf, wgtT2);
    k_tr    <<<dim3(H_, CIN / 64, B_), dim3(256), 0, stream>>>(input, in_t);
    k_im2col<<<dim3(H_, KK_, B_), dim3(256), 0, stream>>>(in_t, offset, mask, smpT);
    k_gemm  <<<dim3(HW / 64, COUT / 128, B_), dim3(256), 0, stream>>>(wgtT2, smpT, bias1, bias2, mid);
    k_blur  <<<dim3(B_ * COUT), dim3(256), 0, stream>>>(mid, out);
}

// Round 13
// 99.840 us; speedup vs baseline: 1.4482x; 1.4482x over previous
//
#include <hip/hip_runtime.h>
#include <math.h>

typedef __bf16 bf16x8 __attribute__((ext_vector_type(8)));
typedef float  f32x4  __attribute__((ext_vector_type(4)));

#define B_    4
#define CIN   256
#define COUT  256
#define KK_   9
#define SD    512
#define H_    64
#define W_    64
#define HW    4096
#define KTOT  2304   // KK_*CIN ; k = kk*CIN + c
#define SCALE_     0.0208333333333333332f   // 1/sqrt(256*9)
#define MOD_SCALE_ 0.04419417382415922f     // 1/sqrt(512)
#define SQRT2_     1.4142135623730951f

__device__ __forceinline__ unsigned short f2bf(float f) {
    union { float f; unsigned int u; } v; v.f = f;
    unsigned int r = v.u + 0x7FFFu + ((v.u >> 16) & 1u);   // RNE
    return (unsigned short)(r >> 16);
}

__device__ __forceinline__ void gload_lds16(const void* g, void* l) {
    __builtin_amdgcn_global_load_lds(
        (const __attribute__((address_space(1))) unsigned int*)g,
        (__attribute__((address_space(3))) unsigned int*)l, 16, 0, 0);
}

// ---------------- kernel 1: style modulation ----------------
__global__ void k_style(const float* __restrict__ style, const float* __restrict__ mod_w,
                        const float* __restrict__ mod_b, float* __restrict__ s_buf) {
    int b = blockIdx.x, c = threadIdx.x;
    const float* st = style + b * SD;
    const float* mw = mod_w + c * SD;
    float acc = 0.f;
    for (int d = 0; d < SD; ++d) acc += st[d] * mw[d];
    s_buf[b * CIN + c] = acc * MOD_SCALE_ + mod_b[c];
}

// ---------------- kernel 2: demodulated weights, bf16, o-major, coalesced stores ----
// wgtT2[b][o][k], k = kk*CIN + c
__global__ void k_wgt(const float* __restrict__ weight, const float* __restrict__ s_buf,
                      unsigned short* __restrict__ wgtT2) {
    int o = blockIdx.x, b = blockIdx.y;
    int c = threadIdx.x;
    float s = s_buf[b * CIN + c];
    const float* wp = weight + (o * CIN + c) * KK_;
    float w[KK_];
    float p = 0.f;
#pragma unroll
    for (int i = 0; i < KK_; ++i) { w[i] = SCALE_ * wp[i] * s; p += w[i] * w[i]; }
    __shared__ float red[256];
    red[c] = p;
    __syncthreads();
    for (int s2 = 128; s2 > 0; s2 >>= 1) {
        if (c < s2) red[c] += red[c + s2];
        __syncthreads();
    }
    float demod = rsqrtf(red[0] + 1e-8f);
    __shared__ unsigned short wbuf[KK_][256];
#pragma unroll
    for (int i = 0; i < KK_; ++i) wbuf[i][c] = f2bf(w[i] * demod);
    __syncthreads();
    unsigned int* dst = (unsigned int*)(wgtT2 + ((size_t)(b * COUT + o)) * KTOT);
#pragma unroll
    for (int e = 0; e < KK_ / 2 + 1; ++e) {
        int idx = c + e * 256;
        if (idx < (KK_ * 256) / 2) {
            int k0 = idx * 2;
            int kk = k0 >> 8, cc = k0 & 255;
            dst[idx] = (unsigned int)wbuf[kk][cc] | ((unsigned int)wbuf[kk][cc + 1] << 16);
        }
    }
}

// ---------------- kernel 2b: input transpose -> in_t[b][y][x][c] bf16 ----------------
__global__ __launch_bounds__(256) void k_tr(const float* __restrict__ in,
                                            unsigned short* __restrict__ in_t) {
    const int y = blockIdx.x, cc = blockIdx.y, b = blockIdx.z;
    const int tid = threadIdx.x;
    __shared__ unsigned short t[64][65];
    for (int e = tid; e < 4096; e += 256) {
        int c = e >> 6, x = e & 63;
        t[c][x] = f2bf(in[((size_t)(b * CIN + cc * 64 + c)) * HW + y * W_ + x]);
    }
    __syncthreads();
    for (int e = tid; e < 2048; e += 256) {
        int x = e >> 5, cp = e & 31;
        int c = cp * 2;
        unsigned int lo = t[c][x], hi = t[c + 1][x];
        unsigned int v = lo | (hi << 16);
        unsigned int* dst = (unsigned int*)(in_t + ((size_t)(b * HW + y * W_ + x)) * CIN + cc * 64);
        dst[cp] = v;
    }
}

// ---------------- kernel 3: deformable im2col -> smpT[b][p][k] bf16 ----------------
// grid (64 y, 9 kk, 4 b), block 256 = 4 waves.
__global__ __launch_bounds__(256) void k_im2col(
    const unsigned short* __restrict__ in_t, const float* __restrict__ off,
    const float* __restrict__ msk, unsigned short* __restrict__ smpT) {
    const int y  = blockIdx.x;
    const int kk = blockIdx.y;
    const int b  = blockIdx.z;
    const int tid = threadIdx.x;

    __shared__ float stw[4][64];
    __shared__ int   stix[4][64];   // pre-scaled by CIN

    if (tid < 64) {
        int x = tid;
        float oy = off[(((size_t)b * 2 * KK_ + 2 * kk + 0) * H_ + y) * W_ + x];
        float ox = off[(((size_t)b * 2 * KK_ + 2 * kk + 1) * H_ + y) * W_ + x];
        float m  = msk[(((size_t)b * KK_ + kk) * H_ + y) * W_ + x];
        float py = (float)(y + kk / 3 - 1) + oy;
        float px = (float)(x + kk % 3 - 1) + ox;
        float y0f = floorf(py), x0f = floorf(px);
        float dy = py - y0f, dx = px - x0f;
        int y0 = (int)y0f, x0 = (int)x0f;
        int y1 = y0 + 1, x1 = x0 + 1;
        bool vy0 = (y0 >= 0) & (y0 < H_), vy1 = (y1 >= 0) & (y1 < H_);
        bool vx0 = (x0 >= 0) & (x0 < W_), vx1 = (x1 >= 0) & (x1 < W_);
        int cy0 = min(max(y0, 0), H_ - 1), cy1 = min(max(y1, 0), H_ - 1);
        int cx0 = min(max(x0, 0), W_ - 1), cx1 = min(max(x1, 0), W_ - 1);
        float wy0 = 1.f - dy, wy1 = dy, wx0 = 1.f - dx, wx1 = dx;
        stw[0][x] = (vy0 && vx0) ? m * wy0 * wx0 : 0.f;  stix[0][x] = (cy0 * W_ + cx0) * CIN;
        stw[1][x] = (vy0 && vx1) ? m * wy0 * wx1 : 0.f;  stix[1][x] = (cy0 * W_ + cx1) * CIN;
        stw[2][x] = (vy1 && vx0) ? m * wy1 * wx0 : 0.f;  stix[2][x] = (cy1 * W_ + cx0) * CIN;
        stw[3][x] = (vy1 && vx1) ? m * wy1 * wx1 : 0.f;  stix[3][x] = (cy1 * W_ + cx1) * CIN;
    }
    __syncthreads();

    const unsigned short* base = in_t + (size_t)b * HW * CIN;
    const int l = tid & 63, w = tid >> 6;
    const int c0 = (l & 31) * 8;
    const int psub = l >> 5;
    unsigned short* drow = smpT + ((size_t)(b * HW + y * W_)) * KTOT + kk * CIN + c0;

#pragma unroll
    for (int i = 0; i < 4; ++i) {
        int pA = (w + i * 8) * 2 + psub;          // 0..63
        int pB = (w + i * 8 + 4) * 2 + psub;
        bf16x8 a0 = *(const bf16x8*)(base + stix[0][pA] + c0);
        bf16x8 a1 = *(const bf16x8*)(base + stix[1][pA] + c0);
        bf16x8 a2 = *(const bf16x8*)(base + stix[2][pA] + c0);
        bf16x8 a3 = *(const bf16x8*)(base + stix[3][pA] + c0);
        bf16x8 b0 = *(const bf16x8*)(base + stix[0][pB] + c0);
        bf16x8 b1 = *(const bf16x8*)(base + stix[1][pB] + c0);
        bf16x8 b2 = *(const bf16x8*)(base + stix[2][pB] + c0);
        bf16x8 b3 = *(const bf16x8*)(base + stix[3][pB] + c0);
        float wa0 = stw[0][pA], wa1 = stw[1][pA], wa2 = stw[2][pA], wa3 = stw[3][pA];
        float wb0 = stw[0][pB], wb1 = stw[1][pB], wb2 = stw[2][pB], wb3 = stw[3][pB];
        bf16x8 rA, rB;
#pragma unroll
        for (int j = 0; j < 8; ++j) {
            rA[j] = (__bf16)(wa0 * (float)a0[j] + wa1 * (float)a1[j]
                           + wa2 * (float)a2[j] + wa3 * (float)a3[j]);
            rB[j] = (__bf16)(wb0 * (float)b0[j] + wb1 * (float)b1[j]
                           + wb2 * (float)b2[j] + wb3 * (float)b3[j]);
        }
        *(bf16x8*)(drow + (size_t)pA * KTOT) = rA;
        *(bf16x8*)(drow + (size_t)pB * KTOT) = rB;
    }
}

// ---------------- kernel 4: bf16 MFMA GEMM, 8 waves, triple-buffer + counted vmcnt ----
// C[o][p] = sum_k W[o][k] * S[p][k]. Tile 128(O) x 64(P), BK=64, 8 waves (wave 32x32).
// 72 KB LDS -> 2 blocks/CU = 16 waves/CU (TLP is the dominant lever — r11/r8 data).
// Counted s_waitcnt vmcnt: 2 stages (3 loads each) stay in flight across barriers.
__global__ __launch_bounds__(512) void k_gemm(
    const unsigned short* __restrict__ wgtT2, const unsigned short* __restrict__ smpT,
    const float* __restrict__ bias1, const float* __restrict__ bias2,
    float* __restrict__ mid) {
    const int p0 = blockIdx.x * 64;
    const int o0 = blockIdx.y * 128;
    const int b  = blockIdx.z;
    const int tid = threadIdx.x;
    const int w  = tid >> 6, l = tid & 63;
    const int lo = l & 15, lg = l >> 4;
    const int wo = w >> 1, wp = w & 1;     // wave tile: 32 o x 32 p

    __shared__ unsigned short a_lds[3][128 * 64];   // 48 KB [o][k]
    __shared__ unsigned short b_lds[3][64 * 64];    // 24 KB [p][k]

    const unsigned short* Abase = wgtT2 + ((size_t)(b * COUT + o0)) * KTOT;
    const unsigned short* Bbase = smpT  + ((size_t)(b * HW   + p0)) * KTOT;

    f32x4 acc[2][2] = {};

    // staging: 512 threads; A 16KB = 1024 slots (2/thread), B 8KB = 512 slots (1/thread)
    // => 3 gload_lds per thread per STAGE
#define STAGE(T, PB)                                                                     \
    do {                                                                                 \
        int kbase = (T) * 64;                                                            \
        _Pragma("unroll")                                                                \
        for (int i = 0; i < 2; ++i) {                                                    \
            int slin = i * 512 + tid;                                                    \
            int r = slin >> 3, s = slin & 7;                                             \
            gload_lds16(Abase + (size_t)r * KTOT + kbase + ((s ^ (r & 7)) * 8),          \
                        &a_lds[PB][(size_t)slin * 8]);                                   \
        }                                                                                \
        {                                                                                \
            int r = tid >> 3, s = tid & 7;                                               \
            gload_lds16(Bbase + (size_t)r * KTOT + kbase + ((s ^ (r & 7)) * 8),          \
                        &b_lds[PB][(size_t)tid * 8]);                                    \
        }                                                                                \
    } while (0)

#define COMPUTE(PB)                                                                      \
    do {                                                                                 \
        bf16x8 af[2][2], bfr[2][2];                                                      \
        _Pragma("unroll")                                                                \
        for (int mi = 0; mi < 2; ++mi) {                                                 \
            int R = wo * 32 + mi * 16 + lo;                                              \
            _Pragma("unroll")                                                            \
            for (int kki = 0; kki < 2; ++kki)                                            \
                af[mi][kki] = *(const bf16x8*)&a_lds[PB][R * 64 + (((kki * 4 + lg) ^ (R & 7)) * 8)]; \
        }                                                                                \
        _Pragma("unroll")                                                                \
        for (int ni = 0; ni < 2; ++ni) {                                                 \
            int P = wp * 32 + ni * 16 + lo;                                              \
            _Pragma("unroll")                                                            \
            for (int kki = 0; kki < 2; ++kki)                                            \
                bfr[ni][kki] = *(const bf16x8*)&b_lds[PB][P * 64 + (((kki * 4 + lg) ^ (P & 7)) * 8)]; \
        }                                                                                \
        _Pragma("unroll")                                                                \
        for (int kki = 0; kki < 2; ++kki)                                                \
            _Pragma("unroll")                                                            \
            for (int mi = 0; mi < 2; ++mi)                                               \
                _Pragma("unroll")                                                        \
                for (int ni = 0; ni < 2; ++ni)                                           \
                    acc[mi][ni] = __builtin_amdgcn_mfma_f32_16x16x32_bf16(               \
                        af[mi][kki], bfr[ni][kki], acc[mi][ni], 0, 0, 0);                \
    } while (0)

    // prologue: stage tiles 0,1
    STAGE(0, 0);
    STAGE(1, 1);

    int ib0 = 0, ib1 = 1, ib2 = 2;   // compute buf, mid buf, stage buf
    for (int t = 0; t < 34; ++t) {
        // protect ib2 (computed at t-1; t+2 == t-1 mod 3) from the overwrite below
        __builtin_amdgcn_s_barrier();
        STAGE(t + 2, ib2);
        // wait for stage t (oldest 3); t+1,t+2 (6) stay in flight
        asm volatile("s_waitcnt vmcnt(6)" ::: "memory");
        __builtin_amdgcn_sched_barrier(0);
        __builtin_amdgcn_s_barrier();
        COMPUTE(ib0);
        int tmp = ib0; ib0 = ib1; ib1 = ib2; ib2 = tmp;
    }
    // epilogue: tiles 34 (buf ib0), 35 (buf ib1)
    asm volatile("s_waitcnt vmcnt(3)" ::: "memory");
    __builtin_amdgcn_sched_barrier(0);
    __builtin_amdgcn_s_barrier();
    COMPUTE(ib0);
    asm volatile("s_waitcnt vmcnt(0)" ::: "memory");
    __builtin_amdgcn_sched_barrier(0);
    __builtin_amdgcn_s_barrier();
    COMPUTE(ib1);
#undef STAGE
#undef COMPUTE

    // epilogue: frag D mapping col=lo (p), row=lg*4+r (o)
    float* mb = mid + ((size_t)b * COUT) * HW;
#pragma unroll
    for (int mi = 0; mi < 2; ++mi) {
        int obase = o0 + wo * 32 + mi * 16 + lg * 4;
#pragma unroll
        for (int ni = 0; ni < 2; ++ni) {
            int p = p0 + wp * 32 + ni * 16 + lo;
#pragma unroll
            for (int r = 0; r < 4; ++r) {
                int oo = obase + r;
                float v = acc[mi][ni][r] + bias1[oo];
                v = (v > 0.f ? v : 0.2f * v) * SQRT2_;
                v += bias2[oo];
                v = (v > 0.f ? v : 0.2f * v) * SQRT2_;
                mb[(size_t)oo * HW + p] = v;
            }
        }
    }
}

// ---------------- kernel 5: separable x2-upsample FIR blur ----------------
__global__ __launch_bounds__(256) void k_blur(const float* __restrict__ mid,
                                              float* __restrict__ out) {
    const int bo = blockIdx.x;
    const int tid = threadIdx.x;
    __shared__ float m[64][64];
    __shared__ float vt[128][65];

    const float4* src = (const float4*)(mid + (size_t)bo * HW);
#pragma unroll
    for (int i = 0; i < 4; ++i)
        ((float4*)m)[tid + 256 * i] = src[tid + 256 * i];
    __syncthreads();

#pragma unroll
    for (int i = 0; i < 32; ++i) {
        int e = tid + 256 * i;
        int Y = e >> 6, x = e & 63;
        int h = Y >> 1;
        float acc;
        if (Y & 1) acc = 3.f * m[h][x] + ((h + 1 < 64) ? m[h + 1][x] : 0.f);
        else       acc = ((h >= 1) ? m[h - 1][x] : 0.f) + 3.f * m[h][x];
        vt[Y][x] = acc;
    }
    __syncthreads();

    float4* dst = (float4*)(out + (size_t)bo * 128 * 128);
#pragma unroll
    for (int i = 0; i < 16; ++i) {
        int e = tid + 256 * i;
        int Y = e >> 5, t = e & 31;
        const float* v = vt[Y];
        int c = 2 * t;
        float vm1 = (c >= 1) ? v[c - 1] : 0.f;
        float v0 = v[c];
        float v1 = v[c + 1];
        float vp2 = (c + 2 < 64) ? v[c + 2] : 0.f;
        float4 r;
        r.x = (vm1 + 3.f * v0) * (1.f / 16.f);
        r.y = (3.f * v0 + v1)  * (1.f / 16.f);
        r.z = (v0 + 3.f * v1)  * (1.f / 16.f);
        r.w = (3.f * v1 + vp2) * (1.f / 16.f);
        dst[e] = r;
    }
}

// ---------------- launch ----------------
extern "C" void kernel_launch(void* const* d_in, const int* in_sizes, int n_in,
                              void* d_out, int out_size, void* d_ws, size_t ws_size,
                              hipStream_t stream) {
    const float* input  = (const float*)d_in[0];
    const float* style  = (const float*)d_in[1];
    const float* offset = (const float*)d_in[2];
    const float* mask   = (const float*)d_in[3];
    const float* weight = (const float*)d_in[4];
    const float* mod_w  = (const float*)d_in[5];
    const float* mod_b  = (const float*)d_in[6];
    const float* bias1  = (const float*)d_in[7];
    const float* bias2  = (const float*)d_in[8];
    float* out = (float*)d_out;

    // ws layout (bytes): s_buf 4K | wgtT2 bf16 4.72M | smpT bf16 75.5M | X 16.8M
    // X region: in_t bf16 (8.4M, dead after k_im2col) aliased with mid f32 (16.8M).
    char* ws = (char*)d_ws;
    float*          s_buf = (float*)ws;
    unsigned short* wgtT2 = (unsigned short*)(ws + 4096);
    unsigned short* smpT  = (unsigned short*)(ws + 4096 + (size_t)B_ * COUT * KTOT * 2);
    char*           X     = ws + 4096 + (size_t)B_ * COUT * KTOT * 2 + (size_t)B_ * HW * KTOT * 2;
    unsigned short* in_t  = (unsigned short*)X;
    float*          mid   = (float*)X;

    k_style <<<dim3(B_), dim3(256), 0, stream>>>(style, mod_w, mod_b, s_buf);
    k_wgt   <<<dim3(COUT, B_), dim3(256), 0, stream>>>(weight, s_buf, wgtT2);
    k_tr    <<<dim3(H_, CIN / 64, B_), dim3(256), 0, stream>>>(input, in_t);
    k_im2col<<<dim3(H_, KK_, B_), dim3(256), 0, stream>>>(in_t, offset, mask, smpT);
    k_gemm  <<<dim3(HW / 64, COUT / 128, B_), dim3(512), 0, stream>>>(wgtT2, smpT, bias1, bias2, mid);
    k_blur  <<<dim3(B_ * COUT), dim3(256), 0, stream>>>(mid, out);
}